// Round 2
// baseline (299.471 us; speedup 1.0000x reference)
//
#include <hip/hip_runtime.h>
#include <hip/hip_bf16.h>

#define N_NODES 100000
#define NFEA    128
#define HDIM    64
#define E_ORIG  1600000
#define E_CAND  800000
#define E_TOT   2400000

// flat f32 output offsets (elements), reference return order
#define OFF_REPS 0
#define OFF_PRED 6400000
#define OFF_TEI  8000000
#define OFF_EI   12800000

__device__ __forceinline__ float blo(unsigned int u) { return __uint_as_float(u << 16); }
__device__ __forceinline__ float bhi(unsigned int u) { return __uint_as_float(u & 0xFFFF0000u); }

// f32 -> bf16 bits, round-to-nearest-even
__device__ __forceinline__ unsigned short f_to_bf16(float f) {
    unsigned int x = __float_as_uint(f);
    unsigned int r = (x + 0x7FFFu + ((x >> 16) & 1u)) >> 16;
    return (unsigned short)r;
}
// round f32 through bf16 and back (to match bf16-rounded reference indices)
__device__ __forceinline__ float bf16_round(float f) {
    return __uint_as_float(((unsigned int)f_to_bf16(f)) << 16);
}

// load 4 consecutive float values from a buffer that is either f32 or bf16
__device__ __forceinline__ void load4f(const void* p, int off, bool isbf16, float* o) {
    if (isbf16) {
        uint2 u = *(const uint2*)((const unsigned short*)p + off);
        o[0] = blo(u.x); o[1] = bhi(u.x); o[2] = blo(u.y); o[3] = bhi(u.y);
    } else {
        float4 v = *(const float4*)((const float*)p + off);
        o[0] = v.x; o[1] = v.y; o[2] = v.z; o[3] = v.w;
    }
}

// wave-uniform probe: is this float buffer bf16-coerced? (call with full wave active)
__device__ __forceinline__ bool detect_bf16(const void* p) {
    int lane = threadIdx.x & 63;
    unsigned int probe = ((const unsigned int*)p)[lane];
    float lowf = blo(probe);
    bool plaus = (lowf == lowf) && (fabsf(lowf) > 0.001f) && (fabsf(lowf) < 64.0f);
    unsigned long long bm = __ballot(plaus);
    return (__popcll(bm) >= 32);
}

// wave-uniform probe: is this index buffer int64? (high words of small indices == 0)
__device__ __forceinline__ bool detect_i64(const int* p) {
    int lane = threadIdx.x & 63;
    int w = p[lane];
    unsigned long long bm = __ballot(w != 0);
    return (bm & 0xAAAAAAAAAAAAAAAAull) == 0ull;  // all odd words zero -> int64
}

__device__ __forceinline__ int idx_load(const int* p, size_t li, bool is64) {
    return is64 ? p[2 * li] : p[li];  // little-endian low word; indices < 2^17
}

// ---------------------------------------------------------------------------
// Kernel 1: representations = relu(feat @ W1 + b1) @ W2 + b2, written as f32.
// 64 rows per block, 256 threads (4 waves, 16 rows/wave), 4x4 reg tile/lane.
// ---------------------------------------------------------------------------
__global__ void __launch_bounds__(256)
mlp_kernel(const void* __restrict__ feats,
           const void* __restrict__ W1, const void* __restrict__ b1,
           const void* __restrict__ W2, const void* __restrict__ b2,
           float* __restrict__ out_reps)
{
    __shared__ float featLds[64][NFEA + 4];
    __shared__ float hLds[64][HDIM + 4];

    const int t       = threadIdx.x;
    const int lane    = t & 63;
    const int wv      = t >> 6;
    const int rowBase = blockIdx.x * 64;

    const bool isbf16 = detect_bf16(feats);   // assume uniform coercion for W/b too

    // stage 64 x 128 feature tile into LDS as f32
    for (int idx = t; idx < 64 * 32; idx += 256) {
        int r = idx >> 5, q = idx & 31;
        int gr = rowBase + r;
        float v0 = 0.f, v1 = 0.f, v2 = 0.f, v3 = 0.f;
        if (gr < N_NODES) {
            if (isbf16) {
                uint2 u = ((const uint2*)feats)[gr * 32 + q];
                v0 = blo(u.x); v1 = bhi(u.x); v2 = blo(u.y); v3 = bhi(u.y);
            } else {
                float4 v = ((const float4*)feats)[gr * 32 + q];
                v0 = v.x; v1 = v.y; v2 = v.z; v3 = v.w;
            }
        }
        featLds[r][q * 4 + 0] = v0; featLds[r][q * 4 + 1] = v1;
        featLds[r][q * 4 + 2] = v2; featLds[r][q * 4 + 3] = v3;
    }
    __syncthreads();

    const int rowg = lane >> 4;
    const int colg = lane & 15;
    const int r0 = wv * 16 + rowg * 4;
    const int c0 = colg * 4;

    // phase A: h = relu(feat @ W1 + b1)
    float acc[4][4];
    {
        float bb[4];
        load4f(b1, c0, isbf16, bb);
        #pragma unroll
        for (int r = 0; r < 4; ++r)
            #pragma unroll
            for (int c = 0; c < 4; ++c) acc[r][c] = bb[c];
    }
    for (int kk = 0; kk < NFEA; kk += 4) {
        float fr[4][4];
        #pragma unroll
        for (int r = 0; r < 4; ++r) {
            float4 v = *(const float4*)&featLds[r0 + r][kk];
            fr[r][0] = v.x; fr[r][1] = v.y; fr[r][2] = v.z; fr[r][3] = v.w;
        }
        float wr[4][4];
        #pragma unroll
        for (int q = 0; q < 4; ++q) load4f(W1, (kk + q) * HDIM + c0, isbf16, wr[q]);
        #pragma unroll
        for (int q = 0; q < 4; ++q)
            #pragma unroll
            for (int r = 0; r < 4; ++r)
                #pragma unroll
                for (int c = 0; c < 4; ++c)
                    acc[r][c] = fmaf(fr[r][q], wr[q][c], acc[r][c]);
    }
    #pragma unroll
    for (int r = 0; r < 4; ++r) {
        float4 hv;
        hv.x = fmaxf(acc[r][0], 0.f); hv.y = fmaxf(acc[r][1], 0.f);
        hv.z = fmaxf(acc[r][2], 0.f); hv.w = fmaxf(acc[r][3], 0.f);
        *(float4*)&hLds[r0 + r][c0] = hv;
    }
    __syncthreads();

    // phase B: reps = h @ W2 + b2
    float acc2[4][4];
    {
        float bb[4];
        load4f(b2, c0, isbf16, bb);
        #pragma unroll
        for (int r = 0; r < 4; ++r)
            #pragma unroll
            for (int c = 0; c < 4; ++c) acc2[r][c] = bb[c];
    }
    for (int kk = 0; kk < HDIM; kk += 4) {
        float fr[4][4];
        #pragma unroll
        for (int r = 0; r < 4; ++r) {
            float4 v = *(const float4*)&hLds[r0 + r][kk];
            fr[r][0] = v.x; fr[r][1] = v.y; fr[r][2] = v.z; fr[r][3] = v.w;
        }
        float wr[4][4];
        #pragma unroll
        for (int q = 0; q < 4; ++q) load4f(W2, (kk + q) * HDIM + c0, isbf16, wr[q]);
        #pragma unroll
        for (int q = 0; q < 4; ++q)
            #pragma unroll
            for (int r = 0; r < 4; ++r)
                #pragma unroll
                for (int c = 0; c < 4; ++c)
                    acc2[r][c] = fmaf(fr[r][q], wr[q][c], acc2[r][c]);
    }

    // write reps as f32 (16B stores)
    #pragma unroll
    for (int r = 0; r < 4; ++r) {
        int gr = rowBase + r0 + r;
        if (gr < N_NODES) {
            float4 v;
            v.x = acc2[r][0]; v.y = acc2[r][1]; v.z = acc2[r][2]; v.w = acc2[r][3];
            *(float4*)(out_reps + (size_t)gr * HDIM + c0) = v;
        }
    }
}

// ---------------------------------------------------------------------------
// Kernel 2: predictor_weights[e] = relu(<reps[src], reps[dst]>), orig edges
// only. 16 lanes/edge, float4 per lane per endpoint (row = 2 cachelines).
// ---------------------------------------------------------------------------
__global__ void __launch_bounds__(256)
edge_dot_kernel(const int* __restrict__ eidx,
                const float* __restrict__ reps,
                float* __restrict__ out_pred)
{
    const bool is64 = detect_i64(eidx);
    int t = blockIdx.x * 256 + threadIdx.x;   // exactly E_ORIG*16 threads
    int e = t >> 4;
    int g = t & 15;
    int s = idx_load(eidx, (size_t)e, is64);
    int d = idx_load(eidx, (size_t)E_ORIG + e, is64);
    float4 a = *((const float4*)(reps + (size_t)s * HDIM) + g);
    float4 b = *((const float4*)(reps + (size_t)d * HDIM) + g);
    float dot = a.x * b.x;
    dot = fmaf(a.y, b.y, dot);
    dot = fmaf(a.z, b.z, dot);
    dot = fmaf(a.w, b.w, dot);
    dot += __shfl_xor(dot, 1);
    dot += __shfl_xor(dot, 2);
    dot += __shfl_xor(dot, 4);
    dot += __shfl_xor(dot, 8);
    if (g == 0) out_pred[e] = fmaxf(dot, 0.f);
}

// ---------------------------------------------------------------------------
// Kernel 3: total_edge_index (2 x 2.4M) and edge_index (2 x 1.6M) as f32,
// round-tripped through bf16 to match the bf16-rounded reference exactly.
// Exactly 8,000,000 threads.
// ---------------------------------------------------------------------------
__global__ void __launch_bounds__(256)
idx_out_kernel(const int* __restrict__ eidx, const int* __restrict__ pidx,
               float* __restrict__ out_tei,
               float* __restrict__ out_ei)
{
    const bool is64 = detect_i64(eidx);
    int i = blockIdx.x * 256 + threadIdx.x;
    if (i < 2 * E_TOT) {
        int row = (i >= E_TOT) ? 1 : 0;
        int c = i - row * E_TOT;
        int v = (c < E_ORIG) ? idx_load(eidx, (size_t)row * E_ORIG + c, is64)
                             : idx_load(pidx, (size_t)row * E_CAND + (c - E_ORIG), is64);
        out_tei[i] = bf16_round((float)v);
    } else {
        int j = i - 2 * E_TOT;
        out_ei[j] = bf16_round((float)idx_load(eidx, (size_t)j, is64));
    }
}

extern "C" void kernel_launch(void* const* d_in, const int* in_sizes, int n_in,
                              void* d_out, int out_size, void* d_ws, size_t ws_size,
                              hipStream_t stream) {
    const void* feats = d_in[0];                 // (100000,128) f32 or bf16
    const int*  eidx  = (const int*)d_in[1];     // (2,1.6M) int32 or int64
    const int*  pidx  = (const int*)d_in[2];     // (2,0.8M) int32 or int64
    const void* W1    = d_in[3];
    const void* b1    = d_in[4];
    const void* W2    = d_in[5];
    const void* b2    = d_in[6];

    float* out      = (float*)d_out;             // f32 buffer, 16,000,000 elems
    float* out_reps = out + OFF_REPS;
    float* out_pred = out + OFF_PRED;
    float* out_tei  = out + OFF_TEI;
    float* out_ei   = out + OFF_EI;

    // 1) MLP: representations
    int mlp_blocks = (N_NODES + 63) / 64;        // 1563
    mlp_kernel<<<mlp_blocks, 256, 0, stream>>>(feats, W1, b1, W2, b2, out_reps);

    // 2) edge dot products for orig edges (16 lanes per edge, exact grid)
    int dot_blocks = (E_ORIG * 16) / 256;        // 100000
    edge_dot_kernel<<<dot_blocks, 256, 0, stream>>>(eidx, out_reps, out_pred);

    // 3) index copies (independent of 1 and 2)
    int idx_blocks = (2 * E_TOT + 2 * E_ORIG) / 256;  // 31250
    idx_out_kernel<<<idx_blocks, 256, 0, stream>>>(eidx, pidx, out_tei, out_ei);
}